// Round 1
// baseline (1055.346 us; speedup 1.0000x reference)
//
#include <hip/hip_runtime.h>

#define B_  16
#define T_  512
#define M_  2048
#define C_  512
#define NEGV (-1e30f)
#define L2E 1.4426950408889634f
#define LN2 0.69314718055994531f

typedef unsigned short u16;
typedef unsigned int   u32;
using bf16x8 = __attribute__((ext_vector_type(8))) short;
using f32x4  = __attribute__((ext_vector_type(4))) float;

__device__ __forceinline__ float lae(float a, float b) {
  float mx = fmaxf(a, b);
  float d  = fabsf(a - b);
  float e  = __builtin_amdgcn_exp2f(d * (-L2E));
  return mx + LN2 * __builtin_amdgcn_logf(1.0f + e);
}

__device__ __forceinline__ u16 f2bf(float x) {
  u32 u = __float_as_uint(x);
  return (u16)((u + 0x7FFFu + ((u >> 16) & 1u)) >> 16);
}

// ---------------------------------------------------------------------------
// K1: energy GEMM (bf16 MFMA) + gumbel + /temperature -> log_e [B,T,M]
// ---------------------------------------------------------------------------
__launch_bounds__(256)
__global__ void k1_energy(const float* __restrict__ text, const float* __restrict__ mel,
                          const float* __restrict__ noise, const float* __restrict__ ratio,
                          float* __restrict__ log_e)
{
  __shared__ __align__(16) short As[128][40];
  __shared__ __align__(16) short Bs[128][40];
  const int b   = blockIdx.z;
  const int t0  = blockIdx.x * 128;
  const int m0  = blockIdx.y * 128;
  const int tid = threadIdx.x;
  const int lane = tid & 63, wid = tid >> 6;
  const int wr = wid >> 1, wc = wid & 1;
  const float* Ab = text + (size_t)b * T_ * C_;
  const float* Bb = mel  + (size_t)b * M_ * C_;
  f32x4 acc[4][4];
#pragma unroll
  for (int i = 0; i < 4; ++i)
#pragma unroll
    for (int j = 0; j < 4; ++j) acc[i][j] = (f32x4){0.f, 0.f, 0.f, 0.f};

  const int kq = (tid & 7) * 4;
  const int rb = tid >> 3;
  for (int kk = 0; kk < C_; kk += 32) {
    __syncthreads();
#pragma unroll
    for (int it = 0; it < 4; ++it) {
      int r = rb + it * 32;
      float4 va = *(const float4*)(Ab + (size_t)(t0 + r) * C_ + kk + kq);
      As[r][kq + 0] = (short)f2bf(va.x); As[r][kq + 1] = (short)f2bf(va.y);
      As[r][kq + 2] = (short)f2bf(va.z); As[r][kq + 3] = (short)f2bf(va.w);
      float4 vb = *(const float4*)(Bb + (size_t)(m0 + r) * C_ + kk + kq);
      Bs[r][kq + 0] = (short)f2bf(vb.x); Bs[r][kq + 1] = (short)f2bf(vb.y);
      Bs[r][kq + 2] = (short)f2bf(vb.z); Bs[r][kq + 3] = (short)f2bf(vb.w);
    }
    __syncthreads();
    const int k0 = (lane >> 4) * 8;
    bf16x8 af[4], bfr[4];
#pragma unroll
    for (int i = 0; i < 4; ++i) {
      af[i]  = *(const bf16x8*)&As[wr * 64 + i * 16 + (lane & 15)][k0];
      bfr[i] = *(const bf16x8*)&Bs[wc * 64 + i * 16 + (lane & 15)][k0];
    }
#pragma unroll
    for (int i = 0; i < 4; ++i)
#pragma unroll
      for (int j = 0; j < 4; ++j)
        acc[i][j] = __builtin_amdgcn_mfma_f32_16x16x32_bf16(af[i], bfr[j], acc[i][j], 0, 0, 0);
  }
  const float invT = 1.0f / (0.1f + 0.9f * ratio[0]);
#pragma unroll
  for (int i = 0; i < 4; ++i) {
#pragma unroll
    for (int j = 0; j < 4; ++j) {
#pragma unroll
      for (int rr = 0; rr < 4; ++rr) {
        int t = t0 + wr * 64 + i * 16 + (lane >> 4) * 4 + rr;
        int m = m0 + wc * 64 + j * 16 + (lane & 15);
        size_t idx = ((size_t)b * T_ + t) * M_ + m;
        float en = acc[i][j][rr] * (1.0f / 512.0f);
        float u  = noise[idx];
        float nl = -LN2 * __builtin_amdgcn_logf(u);    // -ln u  (>0)
        float g  = -LN2 * __builtin_amdgcn_logf(nl);   // -ln(-ln u)
        log_e[idx] = (en + g) * invT;
      }
    }
  }
}

// ---------------------------------------------------------------------------
// K2: log_S = reverse cumulative LSE of log_e along m (per row). 256 thr/row.
// ---------------------------------------------------------------------------
__launch_bounds__(256)
__global__ void k2_logS(const float* __restrict__ log_e, float* __restrict__ log_S)
{
  const size_t row = blockIdx.x;          // b*T + t
  const float* src = log_e + row * M_;
  float* dst = log_S + row * M_;
  const int tid = threadIdx.x, lane = tid & 63, wid = tid >> 6;
  const int c0 = tid * 8;
  float x[8];
  float4 xa = *(const float4*)(src + c0);
  float4 xb = *(const float4*)(src + c0 + 4);
  x[0] = xa.x; x[1] = xa.y; x[2] = xa.z; x[3] = xa.w;
  x[4] = xb.x; x[5] = xb.y; x[6] = xb.z; x[7] = xb.w;
#pragma unroll
  for (int i = 6; i >= 0; --i) x[i] = lae(x[i], x[i + 1]);  // local suffix incl
  float v = x[0];
#pragma unroll
  for (int d = 1; d < 64; d <<= 1) {
    float w = __shfl_down(v, d);
    if (lane < 64 - d) v = lae(v, w);
  }
  float e = __shfl_down(v, 1);
  if (lane == 63) e = NEGV;               // suffix over lanes strictly after
  __shared__ float part[4];
  if (lane == 0) part[wid] = v;
  __syncthreads();
  float we = NEGV;
  for (int w2 = wid + 1; w2 < 4; ++w2) we = lae(we, part[w2]);
  float off = lae(e, we);                 // LSE over cols >= c0+8
  float y[8];
#pragma unroll
  for (int i = 0; i < 8; ++i) y[i] = lae(x[i], off);
  *(float4*)(dst + c0)     = make_float4(y[0], y[1], y[2], y[3]);
  *(float4*)(dst + c0 + 4) = make_float4(y[4], y[5], y[6], y[7]);
}

// ---------------------------------------------------------------------------
// K3: suffix sums of text over t: suffix[b,t,c] = sum_{t'>=t} text[b,t',c]
//     layout [B][T_+1][C], row T_ = 0
// ---------------------------------------------------------------------------
__launch_bounds__(512)
__global__ void k3_suffix(const float* __restrict__ text, float* __restrict__ suffix)
{
  const int b = blockIdx.x, c = threadIdx.x;
  const float* tb = text + (size_t)b * T_ * C_ + c;
  float* sb = suffix + (size_t)b * (T_ + 1) * C_ + c;
  sb[(size_t)T_ * C_] = 0.f;
  float s = 0.f;
  for (int t = T_ - 1; t >= 0; --t) {
    s += tb[(size_t)t * C_];
    sb[(size_t)t * C_] = s;
  }
}

// ---------------------------------------------------------------------------
// K3b: textT[b,c,t] = bf16(text[b,t,c])  (LDS transpose tiles)
// ---------------------------------------------------------------------------
__launch_bounds__(256)
__global__ void k3b_textT(const float* __restrict__ text, u16* __restrict__ textT)
{
  __shared__ u16 tile[64][66];
  const int b  = blockIdx.z;
  const int t0 = blockIdx.x * 64;
  const int c0 = blockIdx.y * 64;
  const int tid = threadIdx.x;
  const int j = tid & 63, i4 = tid >> 6;
#pragma unroll
  for (int it = 0; it < 16; ++it) {
    int i = it * 4 + i4;
    tile[i][j] = f2bf(text[((size_t)b * T_ + t0 + i) * C_ + c0 + j]);
  }
  __syncthreads();
#pragma unroll
  for (int it = 0; it < 16; ++it) {
    int cc = it * 4 + i4;
    textT[((size_t)b * C_ + c0 + cc) * T_ + t0 + j] = tile[j][cc];
  }
}

// ---------------------------------------------------------------------------
// K4: alpha DP (blocks 0..15) and beta DP (blocks 16..31), one block per b.
//     1024 threads, 2 columns/thread, one barrier per t-step.
// ---------------------------------------------------------------------------
__launch_bounds__(1024)
__global__ void k4_dp(const float* __restrict__ log_e, const float* __restrict__ log_S,
                      float* __restrict__ alpha_out, float* __restrict__ beta_out)
{
  __shared__ float part[2][16];
  const int blk = blockIdx.x;
  const int b = blk & 15;
  const int tid = threadIdx.x;
  const int lane = tid & 63, wid = tid >> 6;
  const int c0 = tid * 2;
  const float* LE = log_e + (size_t)b * T_ * M_;
  const float* LS = log_S + (size_t)b * T_ * M_;
  int pb = 0;

  if (blk < 16) {
    // ---- alpha ----
    float* AO = alpha_out + (size_t)b * T_ * M_;
    float a0 = (c0 == 0) ? 0.f : NEGV;
    float a1 = NEGV;
    float2 ls = *(const float2*)(LS + c0);
    float2 le = *(const float2*)(LE + c0);
    float lem1 = (lane == 0 && wid > 0) ? LE[c0 - 1] : 0.f;
    for (int t = 0; t < T_; ++t) {
      const int tn = (t + 1 < T_) ? t + 1 : t;
      float2 lsN = *(const float2*)(LS + (size_t)tn * M_ + c0);
      float2 leN = *(const float2*)(LE + (size_t)tn * M_ + c0);
      float lem1N = (lane == 0 && wid > 0) ? LE[(size_t)tn * M_ + c0 - 1] : 0.f;

      float u0 = a0 - ls.x;
      float u1 = a1 - ls.y;
      float s1 = lae(u0, u1);
      float v = s1;
#pragma unroll
      for (int d = 1; d < 64; d <<= 1) {
        float w = __shfl_up(v, d);
        if (lane >= d) v = lae(v, w);
      }
      float e = __shfl_up(v, 1);
      if (lane == 0) e = NEGV;
      if (lane == 63) part[pb][wid] = v;
      __syncthreads();
      float p = (lane < 16) ? part[pb][lane] : NEGV;
#pragma unroll
      for (int d = 1; d < 16; d <<= 1) {
        float w = __shfl_up(p, d);
        if (lane >= d) p = lae(p, w);
      }
      float wave_excl = (wid == 0) ? NEGV : __shfl(p, wid - 1);
      float P = lae(wave_excl, e);
      float inner0 = lae(P, u0);
      float inner1 = lae(P, s1);
      float out0 = le.x + inner0;
      float out1 = le.y + inner1;
      *(float2*)(AO + (size_t)t * M_ + c0) = make_float2(out0, out1);
      float po = __shfl_up(out1, 1);
      if (lane == 0) po = (wid == 0) ? NEGV : (lem1 + wave_excl);
      a0 = po; a1 = out0;
      ls = lsN; le = leN; lem1 = lem1N;
      pb ^= 1;
    }
  } else {
    // ---- beta ----
    float* BO = beta_out + (size_t)b * T_ * M_;
    float b0 = 0.f;
    float b1 = (c0 + 1 == M_ - 1) ? 1.f : 0.f;   // faithful odd init = 1
    *(float2*)(BO + (size_t)(T_ - 1) * M_ + c0) = make_float2(b0, b1);
    float2 ls = *(const float2*)(LS + (size_t)(T_ - 2) * M_ + c0);
    float2 le = *(const float2*)(LE + (size_t)(T_ - 2) * M_ + c0);
    for (int t = T_ - 2; t >= 0; --t) {
      const int tn = (t > 0) ? t - 1 : 0;
      float2 lsN = *(const float2*)(LS + (size_t)tn * M_ + c0);
      float2 leN = *(const float2*)(LE + (size_t)tn * M_ + c0);

      float v0 = b0 + le.x;
      float v1 = b1 + le.y;
      float s0 = lae(v0, v1);
      float v = s0;
#pragma unroll
      for (int d = 1; d < 64; d <<= 1) {
        float w = __shfl_down(v, d);
        if (lane < 64 - d) v = lae(v, w);
      }
      float e = __shfl_down(v, 1);
      if (lane == 63) e = NEGV;
      if (lane == 0) part[pb][wid] = v;
      __syncthreads();
      float p = (lane < 16) ? part[pb][lane] : NEGV;
#pragma unroll
      for (int d = 1; d < 16; d <<= 1) {
        float w = __shfl_down(p, d);
        if (lane < 16 - d) p = lae(p, w);
      }
      float wave_excl = (wid == 15) ? NEGV : __shfl(p, wid + 1);
      float Q = lae(wave_excl, e);
      float inner1 = lae(Q, v1);
      float inner0 = lae(Q, s0);
      float n0 = inner0 - ls.x;
      float n1 = inner1 - ls.y;
      *(float2*)(BO + (size_t)t * M_ + c0) = make_float2(n0, n1);
      b0 = n0; b1 = n1;
      ls = lsN; le = leN;
      pb ^= 1;
    }
  }
}

// ---------------------------------------------------------------------------
// K6: gamma = alpha+beta; LSE over t; gamma_log written in-place over alpha;
//     gammaT[b,m,t] = bf16(gamma) masked (NEG -> 0), via LDS transpose.
// ---------------------------------------------------------------------------
__launch_bounds__(256)
__global__ void k6_combine(float* __restrict__ alpha_gl, const float* __restrict__ beta,
                           u16* __restrict__ gammaT)
{
  __shared__ float smx[4][64], ssm[4][64];
  __shared__ u16 gtile[64][66];
  const int b  = blockIdx.x >> 5;
  const int m0 = (blockIdx.x & 31) * 64;
  const int tid = threadIdx.x;
  const int mi = tid & 63, ti = tid >> 6;
  const int m = m0 + mi;
  const size_t base = (size_t)b * T_ * M_ + m;

  float mx = -3.0e38f, s = 0.f;
  for (int t = ti; t < T_; t += 4) {
    float g = alpha_gl[base + (size_t)t * M_] + beta[base + (size_t)t * M_];
    if (g > mx) { s = s * __builtin_amdgcn_exp2f((mx - g) * L2E) + 1.f; mx = g; }
    else        { s += __builtin_amdgcn_exp2f((g - mx) * L2E); }
  }
  smx[ti][mi] = mx; ssm[ti][mi] = s;
  __syncthreads();
  float Mv = smx[0][mi], Sv = ssm[0][mi];
#pragma unroll
  for (int k = 1; k < 4; ++k) {
    float Mk = smx[k][mi], Sk = ssm[k][mi];
    if (Mk > Mv) { Sv = Sv * __builtin_amdgcn_exp2f((Mv - Mk) * L2E) + Sk; Mv = Mk; }
    else         { Sv += Sk * __builtin_amdgcn_exp2f((Mk - Mv) * L2E); }
  }
  const float lse = Mv + LN2 * __builtin_amdgcn_logf(Sv);

  for (int tc = 0; tc < T_; tc += 64) {
    for (int tt = ti; tt < 64; tt += 4) {
      size_t idx = base + (size_t)(tc + tt) * M_;
      float g = alpha_gl[idx] + beta[idx];
      alpha_gl[idx] = g - lse;                       // gamma_log in-place
      gtile[mi][tt] = (g <= -1e29f) ? (u16)0 : f2bf(g);
    }
    __syncthreads();
#pragma unroll
    for (int it = 0; it < 16; ++it) {
      int rr = it * 4 + ti;
      gammaT[((size_t)b * M_ + m0 + rr) * T_ + tc + mi] = gtile[rr][mi];
    }
    __syncthreads();
  }
}

// ---------------------------------------------------------------------------
// K7: expanded[b,m,c] = sum_t gammaT[m,t]*textT[c,t]  + (-1e30)*suffix[m+1,c]
// ---------------------------------------------------------------------------
__launch_bounds__(256)
__global__ void k7_expanded(const u16* __restrict__ gammaT, const u16* __restrict__ textT,
                            const float* __restrict__ suffix, float* __restrict__ expanded)
{
  __shared__ __align__(16) short As[128][40];
  __shared__ __align__(16) short Bs[128][40];
  const int b   = blockIdx.z;
  const int m0  = blockIdx.x * 128;
  const int c0  = blockIdx.y * 128;
  const int tid = threadIdx.x;
  const int lane = tid & 63, wid = tid >> 6;
  const int wr = wid >> 1, wc = wid & 1;
  const u16* Ab = gammaT + (size_t)b * M_ * T_;
  const u16* Bb = textT  + (size_t)b * C_ * T_;
  f32x4 acc[4][4];
#pragma unroll
  for (int i = 0; i < 4; ++i)
#pragma unroll
    for (int j = 0; j < 4; ++j) acc[i][j] = (f32x4){0.f, 0.f, 0.f, 0.f};

  const int ko  = (tid & 3) * 8;
  const int rb2 = tid >> 2;
  for (int kk = 0; kk < T_; kk += 32) {
    __syncthreads();
#pragma unroll
    for (int it = 0; it < 2; ++it) {
      int r = rb2 + it * 64;
      *(uint4*)&As[r][ko] = *(const uint4*)(Ab + (size_t)(m0 + r) * T_ + kk + ko);
      *(uint4*)&Bs[r][ko] = *(const uint4*)(Bb + (size_t)(c0 + r) * T_ + kk + ko);
    }
    __syncthreads();
    const int k0 = (lane >> 4) * 8;
    bf16x8 af[4], bfr[4];
#pragma unroll
    for (int i = 0; i < 4; ++i) {
      af[i]  = *(const bf16x8*)&As[wr * 64 + i * 16 + (lane & 15)][k0];
      bfr[i] = *(const bf16x8*)&Bs[wc * 64 + i * 16 + (lane & 15)][k0];
    }
#pragma unroll
    for (int i = 0; i < 4; ++i)
#pragma unroll
      for (int j = 0; j < 4; ++j)
        acc[i][j] = __builtin_amdgcn_mfma_f32_16x16x32_bf16(af[i], bfr[j], acc[i][j], 0, 0, 0);
  }
#pragma unroll
  for (int i = 0; i < 4; ++i) {
#pragma unroll
    for (int j = 0; j < 4; ++j) {
#pragma unroll
      for (int rr = 0; rr < 4; ++rr) {
        int m = m0 + wr * 64 + i * 16 + (lane >> 4) * 4 + rr;
        int c = c0 + wc * 64 + j * 16 + (lane & 15);
        int sidx = (m + 1 < T_) ? (m + 1) : T_;
        float sfx = suffix[((size_t)b * (T_ + 1) + sidx) * C_ + c];
        expanded[((size_t)b * M_ + m) * C_ + c] = acc[i][j][rr] + NEGV * sfx;
      }
    }
  }
}

// ---------------------------------------------------------------------------
extern "C" void kernel_launch(void* const* d_in, const int* in_sizes, int n_in,
                              void* d_out, int out_size, void* d_ws, size_t ws_size,
                              hipStream_t stream) {
  const float* text  = (const float*)d_in[0];
  const float* mel   = (const float*)d_in[1];
  const float* noise = (const float*)d_in[2];
  const float* ratio = (const float*)d_in[3];

  const size_t BTM = (size_t)B_ * T_ * M_;   // 16777216
  float* out       = (float*)d_out;
  float* gamma_log = out;                    // also alpha scratch
  float* expanded  = out + BTM;              // also beta scratch

  char* w = (char*)d_ws;
  float* log_e  = (float*)(w + 0);
  float* log_S  = (float*)(w + 67108864);
  float* suffix = (float*)(w + 134217728);   // [B][T+1][C]  16809984 B
  u16*   textT  = (u16*)  (w + 151027712);   // [B][C][T]     8388608 B
  u16*   gammaT = (u16*)  (w + 159416320);   // [B][M][T]    33554432 B
  // total ws needed: 192970752 bytes

  k1_energy  <<<dim3(4, 16, 16), 256, 0, stream>>>(text, mel, noise, ratio, log_e);
  k2_logS    <<<B_ * T_,        256, 0, stream>>>(log_e, log_S);
  k3_suffix  <<<B_,             512, 0, stream>>>(text, suffix);
  k3b_textT  <<<dim3(8, 8, 16), 256, 0, stream>>>(text, textT);
  k4_dp      <<<32,            1024, 0, stream>>>(log_e, log_S, gamma_log, expanded);
  k6_combine <<<B_ * 32,        256, 0, stream>>>(gamma_log, expanded, gammaT);
  k7_expanded<<<dim3(16, 4, 16),256, 0, stream>>>(gammaT, textT, suffix, expanded);
}

// Round 2
// 930.762 us; speedup vs baseline: 1.1339x; 1.1339x over previous
//
#include <hip/hip_runtime.h>

#define B_  16
#define T_  512
#define M_  2048
#define C_  512
#define NEGV (-1e30f)
#define L2E 1.4426950408889634f
#define LN2 0.69314718055994531f

typedef unsigned short u16;
typedef unsigned int   u32;
using bf16x8 = __attribute__((ext_vector_type(8))) short;
using f32x4  = __attribute__((ext_vector_type(4))) float;

__device__ __forceinline__ float lae(float a, float b) {
  float mx = fmaxf(a, b);
  float d  = fabsf(a - b);
  float e  = __builtin_amdgcn_exp2f(d * (-L2E));
  return mx + LN2 * __builtin_amdgcn_logf(1.0f + e);
}

__device__ __forceinline__ u16 f2bf(float x) {
  u32 u = __float_as_uint(x);
  return (u16)((u + 0x7FFFu + ((u >> 16) & 1u)) >> 16);
}

// 64-lane inclusive add-scan via DPP (row_shr 1/2/4/8, bcast15, bcast31)
__device__ __forceinline__ float wscan_add(float x) {
  x += __int_as_float(__builtin_amdgcn_update_dpp(0, __float_as_int(x), 0x111, 0xF, 0xF, true));
  x += __int_as_float(__builtin_amdgcn_update_dpp(0, __float_as_int(x), 0x112, 0xF, 0xF, true));
  x += __int_as_float(__builtin_amdgcn_update_dpp(0, __float_as_int(x), 0x114, 0xF, 0xF, true));
  x += __int_as_float(__builtin_amdgcn_update_dpp(0, __float_as_int(x), 0x118, 0xF, 0xF, true));
  x += __int_as_float(__builtin_amdgcn_update_dpp(0, __float_as_int(x), 0x142, 0xA, 0xF, true));
  x += __int_as_float(__builtin_amdgcn_update_dpp(0, __float_as_int(x), 0x143, 0xC, 0xF, true));
  return x;
}

// ---------------------------------------------------------------------------
// K1: energy GEMM (bf16 MFMA) + gumbel + /temperature -> log_e [B,T,M]
// ---------------------------------------------------------------------------
__launch_bounds__(256)
__global__ void k1_energy(const float* __restrict__ text, const float* __restrict__ mel,
                          const float* __restrict__ noise, const float* __restrict__ ratio,
                          float* __restrict__ log_e)
{
  __shared__ __align__(16) short As[128][40];
  __shared__ __align__(16) short Bs[128][40];
  const int b   = blockIdx.z;
  const int t0  = blockIdx.x * 128;
  const int m0  = blockIdx.y * 128;
  const int tid = threadIdx.x;
  const int lane = tid & 63, wid = tid >> 6;
  const int wr = wid >> 1, wc = wid & 1;
  const float* Ab = text + (size_t)b * T_ * C_;
  const float* Bb = mel  + (size_t)b * M_ * C_;
  f32x4 acc[4][4];
#pragma unroll
  for (int i = 0; i < 4; ++i)
#pragma unroll
    for (int j = 0; j < 4; ++j) acc[i][j] = (f32x4){0.f, 0.f, 0.f, 0.f};

  const int kq = (tid & 7) * 4;
  const int rb = tid >> 3;
  for (int kk = 0; kk < C_; kk += 32) {
    __syncthreads();
#pragma unroll
    for (int it = 0; it < 4; ++it) {
      int r = rb + it * 32;
      float4 va = *(const float4*)(Ab + (size_t)(t0 + r) * C_ + kk + kq);
      As[r][kq + 0] = (short)f2bf(va.x); As[r][kq + 1] = (short)f2bf(va.y);
      As[r][kq + 2] = (short)f2bf(va.z); As[r][kq + 3] = (short)f2bf(va.w);
      float4 vb = *(const float4*)(Bb + (size_t)(m0 + r) * C_ + kk + kq);
      Bs[r][kq + 0] = (short)f2bf(vb.x); Bs[r][kq + 1] = (short)f2bf(vb.y);
      Bs[r][kq + 2] = (short)f2bf(vb.z); Bs[r][kq + 3] = (short)f2bf(vb.w);
    }
    __syncthreads();
    const int k0 = (lane >> 4) * 8;
    bf16x8 af[4], bfr[4];
#pragma unroll
    for (int i = 0; i < 4; ++i) {
      af[i]  = *(const bf16x8*)&As[wr * 64 + i * 16 + (lane & 15)][k0];
      bfr[i] = *(const bf16x8*)&Bs[wc * 64 + i * 16 + (lane & 15)][k0];
    }
#pragma unroll
    for (int i = 0; i < 4; ++i)
#pragma unroll
      for (int j = 0; j < 4; ++j)
        acc[i][j] = __builtin_amdgcn_mfma_f32_16x16x32_bf16(af[i], bfr[j], acc[i][j], 0, 0, 0);
  }
  const float invT = 1.0f / (0.1f + 0.9f * ratio[0]);
#pragma unroll
  for (int i = 0; i < 4; ++i) {
#pragma unroll
    for (int j = 0; j < 4; ++j) {
#pragma unroll
      for (int rr = 0; rr < 4; ++rr) {
        int t = t0 + wr * 64 + i * 16 + (lane >> 4) * 4 + rr;
        int m = m0 + wc * 64 + j * 16 + (lane & 15);
        size_t idx = ((size_t)b * T_ + t) * M_ + m;
        float en = acc[i][j][rr] * (1.0f / 512.0f);
        float u  = noise[idx];
        float nl = -LN2 * __builtin_amdgcn_logf(u);    // -ln u  (>0)
        float g  = -LN2 * __builtin_amdgcn_logf(nl);   // -ln(-ln u)
        log_e[idx] = (en + g) * invT;
      }
    }
  }
}

// ---------------------------------------------------------------------------
// K2: log_S = reverse cumulative LSE of log_e along m (per row). 256 thr/row.
// ---------------------------------------------------------------------------
__launch_bounds__(256)
__global__ void k2_logS(const float* __restrict__ log_e, float* __restrict__ log_S)
{
  const size_t row = blockIdx.x;          // b*T + t
  const float* src = log_e + row * M_;
  float* dst = log_S + row * M_;
  const int tid = threadIdx.x, lane = tid & 63, wid = tid >> 6;
  const int c0 = tid * 8;
  float x[8];
  float4 xa = *(const float4*)(src + c0);
  float4 xb = *(const float4*)(src + c0 + 4);
  x[0] = xa.x; x[1] = xa.y; x[2] = xa.z; x[3] = xa.w;
  x[4] = xb.x; x[5] = xb.y; x[6] = xb.z; x[7] = xb.w;
#pragma unroll
  for (int i = 6; i >= 0; --i) x[i] = lae(x[i], x[i + 1]);  // local suffix incl
  float v = x[0];
#pragma unroll
  for (int d = 1; d < 64; d <<= 1) {
    float w = __shfl_down(v, d);
    if (lane < 64 - d) v = lae(v, w);
  }
  float e = __shfl_down(v, 1);
  if (lane == 63) e = NEGV;               // suffix over lanes strictly after
  __shared__ float part[4];
  if (lane == 0) part[wid] = v;
  __syncthreads();
  float we = NEGV;
  for (int w2 = wid + 1; w2 < 4; ++w2) we = lae(we, part[w2]);
  float off = lae(e, we);                 // LSE over cols >= c0+8
  float y[8];
#pragma unroll
  for (int i = 0; i < 8; ++i) y[i] = lae(x[i], off);
  *(float4*)(dst + c0)     = make_float4(y[0], y[1], y[2], y[3]);
  *(float4*)(dst + c0 + 4) = make_float4(y[4], y[5], y[6], y[7]);
}

// ---------------------------------------------------------------------------
// K3a: per-chunk partial sums of text over t (chunk = 64 rows)
//      partial[b][ch][c], scratch in ws (log_e region, before k1 runs)
// ---------------------------------------------------------------------------
__launch_bounds__(512)
__global__ void k3a_partial(const float* __restrict__ text, float* __restrict__ partial)
{
  const int b = blockIdx.x >> 3, ch = blockIdx.x & 7, c = threadIdx.x;
  const float* tb = text + (size_t)b * T_ * C_ + (size_t)ch * 64 * C_ + c;
  float s = 0.f;
#pragma unroll 8
  for (int tt = 0; tt < 64; ++tt) s += tb[(size_t)tt * C_];
  partial[((size_t)b * 8 + ch) * C_ + c] = s;
}

// ---------------------------------------------------------------------------
// K3b: suffix[b,t,c] = sum_{t'>=t} text[b,t',c]; layout [B][T+1][C], row T = 0
// ---------------------------------------------------------------------------
__launch_bounds__(512)
__global__ void k3b_suffix(const float* __restrict__ text, const float* __restrict__ partial,
                           float* __restrict__ suffix)
{
  const int b = blockIdx.x >> 3, ch = blockIdx.x & 7, c = threadIdx.x;
  float off = 0.f;
  for (int ch2 = ch + 1; ch2 < 8; ++ch2) off += partial[((size_t)b * 8 + ch2) * C_ + c];
  const float* tb = text + (size_t)b * T_ * C_ + (size_t)ch * 64 * C_ + c;
  float* sb = suffix + (size_t)b * (T_ + 1) * C_ + (size_t)ch * 64 * C_ + c;
  if (ch == 7) sb[(size_t)64 * C_] = 0.f;   // row T_
  float s = off;
  for (int tt = 63; tt >= 0; --tt) {
    s += tb[(size_t)tt * C_];
    sb[(size_t)tt * C_] = s;
  }
}

// ---------------------------------------------------------------------------
// K3t: textT[b,c,t] = bf16(text[b,t,c])  (LDS transpose tiles)
// ---------------------------------------------------------------------------
__launch_bounds__(256)
__global__ void k3t_textT(const float* __restrict__ text, u16* __restrict__ textT)
{
  __shared__ u16 tile[64][66];
  const int b  = blockIdx.z;
  const int t0 = blockIdx.x * 64;
  const int c0 = blockIdx.y * 64;
  const int tid = threadIdx.x;
  const int j = tid & 63, i4 = tid >> 6;
#pragma unroll
  for (int it = 0; it < 16; ++it) {
    int i = it * 4 + i4;
    tile[i][j] = f2bf(text[((size_t)b * T_ + t0 + i) * C_ + c0 + j]);
  }
  __syncthreads();
#pragma unroll
  for (int it = 0; it < 16; ++it) {
    int cc = it * 4 + i4;
    textT[((size_t)b * C_ + c0 + cc) * T_ + t0 + j] = tile[j][cc];
  }
}

// ---------------------------------------------------------------------------
// K4: alpha DP (blocks 0..15) and beta DP (blocks 16..31), one block per b.
//     256 threads, 8 cols/thread, linear-domain scan with running reference C,
//     one barrier per t-step, DPP wave scan, double-buffered row prefetch.
//     Alpha uses the diagonal transform phi_t[q] = alpha_t[q+t] (shift-free).
// ---------------------------------------------------------------------------
__launch_bounds__(256, 1)
__global__ void k4_dp(const float* __restrict__ log_e, const float* __restrict__ log_S,
                      const float* __restrict__ ratio,
                      float* __restrict__ alpha_out, float* __restrict__ beta_out)
{
  __shared__ __align__(16) float sump[2][4];
  const int blk = blockIdx.x;
  const int b   = blk & 15;
  const int tid = threadIdx.x;
  const int lane = tid & 63;
  const int wid  = tid >> 6;
  const int q0 = tid * 8;
  const float invT = 1.0f / (0.1f + 0.9f * ratio[0]);
  const float KB = 18.4413f * invT;     // le_max_bound + |le_min_bound|
  const float* LE = log_e + (size_t)b * T_ * M_;
  const float* LS = log_S + (size_t)b * T_ * M_;

  float lsb[2][8], leb[2][8], un[8], Cv;

  if (blk < 16) {
    // ======================= alpha =======================
    float* AO = alpha_out + (size_t)b * T_ * M_;

#define ALOAD(BUF, R) { \
    const int r_ = (R); \
    const float* pe_ = LE + (size_t)r_ * (M_ + 1) + q0; \
    const float* ps_ = LS + (size_t)r_ * (M_ + 1) + q0; \
    const int lim_ = M_ - r_; \
    _Pragma("unroll") \
    for (int e = 0; e < 8; ++e) { \
      float lev = pe_[e], lsv = ps_[e]; \
      bool oob = (q0 + e) >= lim_; \
      leb[BUF][e] = oob ? 0.f   : lev; \
      lsb[BUF][e] = oob ? 4e30f : lsv; \
    } }

    ALOAD(0, 0)
    ALOAD(1, 1)
    Cv = 3.6258f * invT + 1.0f;
#pragma unroll
    for (int e = 0; e < 8; ++e)
      un[e] = ((q0 + e) == 0 ? 0.f : NEGV) - lsb[0][e];

#define ASTEP(CUR, NXT, PB, TT) { \
    const int t_ = (TT); \
    const float nsC = -Cv * L2E; \
    float ev[8], base[8], lp[8]; \
    _Pragma("unroll") \
    for (int e = 0; e < 8; ++e) { \
      ev[e] = __builtin_amdgcn_exp2f(__builtin_fmaf(un[e], L2E, nsC)); \
      base[e] = leb[CUR][e] + Cv; \
    } \
    float t01 = ev[0]+ev[1], t23 = ev[2]+ev[3], t45 = ev[4]+ev[5], t67 = ev[6]+ev[7]; \
    float t03 = t01+t23, t47 = t45+t67, Te = t03+t47; \
    lp[0]=ev[0]; lp[1]=t01; lp[2]=t01+ev[2]; lp[3]=t03; \
    lp[4]=t03+ev[4]; lp[5]=t03+t45; lp[6]=lp[5]+ev[6]; lp[7]=Te; \
    float v = wscan_add(Te); \
    float excl = v - Te; \
    if (lane == 63) sump[PB][wid] = v; \
    ALOAD(CUR, (t_ + 2 < T_) ? t_ + 2 : T_ - 1) \
    __syncthreads(); \
    float4 sv = *(const float4*)sump[PB]; \
    float S = (sv.x + sv.y) + (sv.z + sv.w); \
    float woff = (wid >= 1 ? sv.x : 0.f) + (wid >= 2 ? sv.y : 0.f) + (wid >= 3 ? sv.z : 0.f); \
    float off = woff + excl; \
    float out[8]; \
    _Pragma("unroll") \
    for (int e = 0; e < 8; ++e) { \
      float pf = fmaxf(off + lp[e], 1e-30f); \
      out[e] = __builtin_fmaf(__builtin_amdgcn_logf(pf), LN2, base[e]); \
    } \
    { float* rowp = AO + (size_t)t_ * M_ + t_ + q0; \
      const int lim2 = M_ - t_; \
      _Pragma("unroll") \
      for (int e = 0; e < 8; ++e) { \
        bool oob = (q0 + e) >= lim2; \
        float* ap = oob ? (rowp + e - M_) : (rowp + e); \
        *ap = oob ? NEGV : out[e]; \
      } } \
    Cv += __builtin_fmaf(__builtin_amdgcn_logf(fmaxf(S, 1e-30f)), LN2, KB); \
    _Pragma("unroll") \
    for (int e = 0; e < 8; ++e) un[e] = out[e] - lsb[NXT][e]; \
  }

    for (int t = 0; t < T_; t += 2) {
      ASTEP(0, 1, 0, t)
      ASTEP(1, 0, 1, t + 1)
    }
  } else {
    // ======================= beta (mirrored indexing) =======================
    float* BO = beta_out + (size_t)b * T_ * M_;

#define BLOAD(BUF, R) { \
    const int r_ = (R); \
    const float* pe_ = LE + (size_t)r_ * M_ + (M_ - 8 - q0); \
    const float* ps_ = LS + (size_t)r_ * M_ + (M_ - 8 - q0); \
    float4 ea = *(const float4*)(pe_ + 4); \
    float4 eb = *(const float4*)(pe_); \
    float4 sa = *(const float4*)(ps_ + 4); \
    float4 sc = *(const float4*)(ps_); \
    leb[BUF][0]=ea.w; leb[BUF][1]=ea.z; leb[BUF][2]=ea.y; leb[BUF][3]=ea.x; \
    leb[BUF][4]=eb.w; leb[BUF][5]=eb.z; leb[BUF][6]=eb.y; leb[BUF][7]=eb.x; \
    lsb[BUF][0]=sa.w; lsb[BUF][1]=sa.z; lsb[BUF][2]=sa.y; lsb[BUF][3]=sa.x; \
    lsb[BUF][4]=sc.w; lsb[BUF][5]=sc.z; lsb[BUF][6]=sc.y; lsb[BUF][7]=sc.x; \
  }

    // init row T-1: beta = 0 except +1.0 at j = M-1 (faithful odd init)
    { float* rowp = BO + (size_t)(T_ - 1) * M_ + (M_ - 8 - q0);
      float i0 = (q0 == 0) ? 1.f : 0.f;
      *(float4*)(rowp + 4) = make_float4(0.f, 0.f, 0.f, i0);
      *(float4*)(rowp)     = make_float4(0.f, 0.f, 0.f, 0.f);
    }

    BLOAD(0, T_ - 2)
    BLOAD(1, T_ - 3)
    Cv = 14.8155f * invT + 1.5f;
#pragma unroll
    for (int e = 0; e < 8; ++e)
      un[e] = ((q0 + e) == 0 ? 1.f : 0.f) + leb[0][e];

#define BSTEP(CUR, NXT, PB, TT) { \
    const int t_ = (TT); \
    const float nsC = -Cv * L2E; \
    float ev[8], base[8], lp[8]; \
    _Pragma("unroll") \
    for (int e = 0; e < 8; ++e) { \
      ev[e] = __builtin_amdgcn_exp2f(__builtin_fmaf(un[e], L2E, nsC)); \
      base[e] = Cv - lsb[CUR][e]; \
    } \
    float t01 = ev[0]+ev[1], t23 = ev[2]+ev[3], t45 = ev[4]+ev[5], t67 = ev[6]+ev[7]; \
    float t03 = t01+t23, t47 = t45+t67, Te = t03+t47; \
    lp[0]=ev[0]; lp[1]=t01; lp[2]=t01+ev[2]; lp[3]=t03; \
    lp[4]=t03+ev[4]; lp[5]=t03+t45; lp[6]=lp[5]+ev[6]; lp[7]=Te; \
    float v = wscan_add(Te); \
    float excl = v - Te; \
    if (lane == 63) sump[PB][wid] = v; \
    BLOAD(CUR, (t_ - 2 >= 0) ? t_ - 2 : 0) \
    __syncthreads(); \
    float4 sv = *(const float4*)sump[PB]; \
    float S = (sv.x + sv.y) + (sv.z + sv.w); \
    float woff = (wid >= 1 ? sv.x : 0.f) + (wid >= 2 ? sv.y : 0.f) + (wid >= 3 ? sv.z : 0.f); \
    float off = woff + excl; \
    float out[8]; \
    _Pragma("unroll") \
    for (int e = 0; e < 8; ++e) { \
      float pf = fmaxf(off + lp[e], 1e-30f); \
      out[e] = __builtin_fmaf(__builtin_amdgcn_logf(pf), LN2, base[e]); \
    } \
    { float* rowp = BO + (size_t)t_ * M_ + (M_ - 8 - q0); \
      *(float4*)(rowp + 4) = make_float4(out[3], out[2], out[1], out[0]); \
      *(float4*)(rowp)     = make_float4(out[7], out[6], out[5], out[4]); } \
    Cv += __builtin_fmaf(__builtin_amdgcn_logf(fmaxf(S, 1e-30f)), LN2, KB); \
    _Pragma("unroll") \
    for (int e = 0; e < 8; ++e) un[e] = out[e] + leb[NXT][e]; \
  }

    int t = T_ - 2;
    while (true) {
      BSTEP(0, 1, 0, t) --t; if (t < 0) break;
      BSTEP(1, 0, 1, t) --t; if (t < 0) break;
    }
  }
}

// ---------------------------------------------------------------------------
// K6: gamma = alpha+beta; LSE over t; gamma_log written in-place over alpha;
//     gammaT[b,m,t] = bf16(gamma) masked (NEG -> 0), via LDS transpose.
// ---------------------------------------------------------------------------
__launch_bounds__(256)
__global__ void k6_combine(float* __restrict__ alpha_gl, const float* __restrict__ beta,
                           u16* __restrict__ gammaT)
{
  __shared__ float smx[4][64], ssm[4][64];
  __shared__ u16 gtile[64][66];
  const int b  = blockIdx.x >> 5;
  const int m0 = (blockIdx.x & 31) * 64;
  const int tid = threadIdx.x;
  const int mi = tid & 63, ti = tid >> 6;
  const int m = m0 + mi;
  const size_t base = (size_t)b * T_ * M_ + m;

  float mx = -3.0e38f, s = 0.f;
  for (int t = ti; t < T_; t += 4) {
    float g = alpha_gl[base + (size_t)t * M_] + beta[base + (size_t)t * M_];
    if (g > mx) { s = s * __builtin_amdgcn_exp2f((mx - g) * L2E) + 1.f; mx = g; }
    else        { s += __builtin_amdgcn_exp2f((g - mx) * L2E); }
  }
  smx[ti][mi] = mx; ssm[ti][mi] = s;
  __syncthreads();
  float Mv = smx[0][mi], Sv = ssm[0][mi];
#pragma unroll
  for (int k = 1; k < 4; ++k) {
    float Mk = smx[k][mi], Sk = ssm[k][mi];
    if (Mk > Mv) { Sv = Sv * __builtin_amdgcn_exp2f((Mv - Mk) * L2E) + Sk; Mv = Mk; }
    else         { Sv += Sk * __builtin_amdgcn_exp2f((Mk - Mv) * L2E); }
  }
  const float lse = Mv + LN2 * __builtin_amdgcn_logf(Sv);

  for (int tc = 0; tc < T_; tc += 64) {
    for (int tt = ti; tt < 64; tt += 4) {
      size_t idx = base + (size_t)(tc + tt) * M_;
      float g = alpha_gl[idx] + beta[idx];
      alpha_gl[idx] = g - lse;                       // gamma_log in-place
      gtile[mi][tt] = (g <= -1e29f) ? (u16)0 : f2bf(g);
    }
    __syncthreads();
#pragma unroll
    for (int it = 0; it < 16; ++it) {
      int rr = it * 4 + ti;
      gammaT[((size_t)b * M_ + m0 + rr) * T_ + tc + mi] = gtile[rr][mi];
    }
    __syncthreads();
  }
}

// ---------------------------------------------------------------------------
// K7: expanded[b,m,c] = sum_t gammaT[m,t]*textT[c,t]  + (-1e30)*suffix[m+1,c]
// ---------------------------------------------------------------------------
__launch_bounds__(256)
__global__ void k7_expanded(const u16* __restrict__ gammaT, const u16* __restrict__ textT,
                            const float* __restrict__ suffix, float* __restrict__ expanded)
{
  __shared__ __align__(16) short As[128][40];
  __shared__ __align__(16) short Bs[128][40];
  const int b   = blockIdx.z;
  const int m0  = blockIdx.x * 128;
  const int c0  = blockIdx.y * 128;
  const int tid = threadIdx.x;
  const int lane = tid & 63, wid = tid >> 6;
  const int wr = wid >> 1, wc = wid & 1;
  const u16* Ab = gammaT + (size_t)b * M_ * T_;
  const u16* Bb = textT  + (size_t)b * C_ * T_;
  f32x4 acc[4][4];
#pragma unroll
  for (int i = 0; i < 4; ++i)
#pragma unroll
    for (int j = 0; j < 4; ++j) acc[i][j] = (f32x4){0.f, 0.f, 0.f, 0.f};

  const int ko  = (tid & 3) * 8;
  const int rb2 = tid >> 2;
  for (int kk = 0; kk < T_; kk += 32) {
    __syncthreads();
#pragma unroll
    for (int it = 0; it < 2; ++it) {
      int r = rb2 + it * 64;
      *(uint4*)&As[r][ko] = *(const uint4*)(Ab + (size_t)(m0 + r) * T_ + kk + ko);
      *(uint4*)&Bs[r][ko] = *(const uint4*)(Bb + (size_t)(c0 + r) * T_ + kk + ko);
    }
    __syncthreads();
    const int k0 = (lane >> 4) * 8;
    bf16x8 af[4], bfr[4];
#pragma unroll
    for (int i = 0; i < 4; ++i) {
      af[i]  = *(const bf16x8*)&As[wr * 64 + i * 16 + (lane & 15)][k0];
      bfr[i] = *(const bf16x8*)&Bs[wc * 64 + i * 16 + (lane & 15)][k0];
    }
#pragma unroll
    for (int i = 0; i < 4; ++i)
#pragma unroll
      for (int j = 0; j < 4; ++j)
        acc[i][j] = __builtin_amdgcn_mfma_f32_16x16x32_bf16(af[i], bfr[j], acc[i][j], 0, 0, 0);
  }
#pragma unroll
  for (int i = 0; i < 4; ++i) {
#pragma unroll
    for (int j = 0; j < 4; ++j) {
#pragma unroll
      for (int rr = 0; rr < 4; ++rr) {
        int m = m0 + wr * 64 + i * 16 + (lane >> 4) * 4 + rr;
        int c = c0 + wc * 64 + j * 16 + (lane & 15);
        int sidx = (m + 1 < T_) ? (m + 1) : T_;
        float sfx = suffix[((size_t)b * (T_ + 1) + sidx) * C_ + c];
        expanded[((size_t)b * M_ + m) * C_ + c] = acc[i][j][rr] + NEGV * sfx;
      }
    }
  }
}

// ---------------------------------------------------------------------------
extern "C" void kernel_launch(void* const* d_in, const int* in_sizes, int n_in,
                              void* d_out, int out_size, void* d_ws, size_t ws_size,
                              hipStream_t stream) {
  const float* text  = (const float*)d_in[0];
  const float* mel   = (const float*)d_in[1];
  const float* noise = (const float*)d_in[2];
  const float* ratio = (const float*)d_in[3];

  const size_t BTM = (size_t)B_ * T_ * M_;   // 16777216
  float* out       = (float*)d_out;
  float* gamma_log = out;                    // also alpha scratch
  float* expanded  = out + BTM;              // also beta scratch

  char* w = (char*)d_ws;
  float* log_e  = (float*)(w + 0);
  float* log_S  = (float*)(w + 67108864);
  float* suffix = (float*)(w + 134217728);   // [B][T+1][C]  16809984 B
  u16*   textT  = (u16*)  (w + 151027712);   // [B][C][T]     8388608 B
  u16*   gammaT = (u16*)  (w + 159416320);   // [B][M][T]    33554432 B
  float* partial = (float*)(w + 0);          // k3 scratch, reuses log_e region (before k1)

  k3a_partial<<<B_ * 8,          512, 0, stream>>>(text, partial);
  k3b_suffix <<<B_ * 8,          512, 0, stream>>>(text, partial, suffix);
  k3t_textT  <<<dim3(8, 8, 16),  256, 0, stream>>>(text, textT);
  k1_energy  <<<dim3(4, 16, 16), 256, 0, stream>>>(text, mel, noise, ratio, log_e);
  k2_logS    <<<B_ * T_,         256, 0, stream>>>(log_e, log_S);
  k4_dp      <<<32,              256, 0, stream>>>(log_e, log_S, ratio, gamma_log, expanded);
  k6_combine <<<B_ * 32,         256, 0, stream>>>(gamma_log, expanded, gammaT);
  k7_expanded<<<dim3(16, 4, 16), 256, 0, stream>>>(gammaT, textT, suffix, expanded);
}

// Round 3
// 756.570 us; speedup vs baseline: 1.3949x; 1.2302x over previous
//
#include <hip/hip_runtime.h>

#define B_  16
#define T_  512
#define M_  2048
#define C_  512
#define NEGV (-1e30f)
#define L2E 1.4426950408889634f
#define LN2 0.69314718055994531f

typedef unsigned short u16;
typedef unsigned int   u32;
using bf16x8 = __attribute__((ext_vector_type(8))) short;
using f32x4  = __attribute__((ext_vector_type(4))) float;

__device__ __forceinline__ float lae(float a, float b) {
  float mx = fmaxf(a, b);
  float d  = fabsf(a - b);
  float e  = __builtin_amdgcn_exp2f(d * (-L2E));
  return mx + LN2 * __builtin_amdgcn_logf(1.0f + e);
}

__device__ __forceinline__ u16 f2bf(float x) {
  u32 u = __float_as_uint(x);
  return (u16)((u + 0x7FFFu + ((u >> 16) & 1u)) >> 16);
}

// 64-lane inclusive add-scan via DPP (row_shr 1/2/4/8, bcast15, bcast31)
__device__ __forceinline__ float wscan_add(float x) {
  x += __int_as_float(__builtin_amdgcn_update_dpp(0, __float_as_int(x), 0x111, 0xF, 0xF, true));
  x += __int_as_float(__builtin_amdgcn_update_dpp(0, __float_as_int(x), 0x112, 0xF, 0xF, true));
  x += __int_as_float(__builtin_amdgcn_update_dpp(0, __float_as_int(x), 0x114, 0xF, 0xF, true));
  x += __int_as_float(__builtin_amdgcn_update_dpp(0, __float_as_int(x), 0x118, 0xF, 0xF, true));
  x += __int_as_float(__builtin_amdgcn_update_dpp(0, __float_as_int(x), 0x142, 0xA, 0xF, true));
  x += __int_as_float(__builtin_amdgcn_update_dpp(0, __float_as_int(x), 0x143, 0xC, 0xF, true));
  return x;
}

// ---------------------------------------------------------------------------
// K1: energy GEMM (bf16 MFMA) + gumbel + /temperature -> log_e [B,T,M]
// ---------------------------------------------------------------------------
__launch_bounds__(256)
__global__ void k1_energy(const float* __restrict__ text, const float* __restrict__ mel,
                          const float* __restrict__ noise, const float* __restrict__ ratio,
                          float* __restrict__ log_e)
{
  __shared__ __align__(16) short As[128][40];
  __shared__ __align__(16) short Bs[128][40];
  const int b   = blockIdx.z;
  const int t0  = blockIdx.x * 128;
  const int m0  = blockIdx.y * 128;
  const int tid = threadIdx.x;
  const int lane = tid & 63, wid = tid >> 6;
  const int wr = wid >> 1, wc = wid & 1;
  const float* Ab = text + (size_t)b * T_ * C_;
  const float* Bb = mel  + (size_t)b * M_ * C_;
  f32x4 acc[4][4];
#pragma unroll
  for (int i = 0; i < 4; ++i)
#pragma unroll
    for (int j = 0; j < 4; ++j) acc[i][j] = (f32x4){0.f, 0.f, 0.f, 0.f};

  const int kq = (tid & 7) * 4;
  const int rb = tid >> 3;
  for (int kk = 0; kk < C_; kk += 32) {
    __syncthreads();
#pragma unroll
    for (int it = 0; it < 4; ++it) {
      int r = rb + it * 32;
      float4 va = *(const float4*)(Ab + (size_t)(t0 + r) * C_ + kk + kq);
      As[r][kq + 0] = (short)f2bf(va.x); As[r][kq + 1] = (short)f2bf(va.y);
      As[r][kq + 2] = (short)f2bf(va.z); As[r][kq + 3] = (short)f2bf(va.w);
      float4 vb = *(const float4*)(Bb + (size_t)(m0 + r) * C_ + kk + kq);
      Bs[r][kq + 0] = (short)f2bf(vb.x); Bs[r][kq + 1] = (short)f2bf(vb.y);
      Bs[r][kq + 2] = (short)f2bf(vb.z); Bs[r][kq + 3] = (short)f2bf(vb.w);
    }
    __syncthreads();
    const int k0 = (lane >> 4) * 8;
    bf16x8 af[4], bfr[4];
#pragma unroll
    for (int i = 0; i < 4; ++i) {
      af[i]  = *(const bf16x8*)&As[wr * 64 + i * 16 + (lane & 15)][k0];
      bfr[i] = *(const bf16x8*)&Bs[wc * 64 + i * 16 + (lane & 15)][k0];
    }
#pragma unroll
    for (int i = 0; i < 4; ++i)
#pragma unroll
      for (int j = 0; j < 4; ++j)
        acc[i][j] = __builtin_amdgcn_mfma_f32_16x16x32_bf16(af[i], bfr[j], acc[i][j], 0, 0, 0);
  }
  const float invT = 1.0f / (0.1f + 0.9f * ratio[0]);
#pragma unroll
  for (int i = 0; i < 4; ++i) {
#pragma unroll
    for (int j = 0; j < 4; ++j) {
#pragma unroll
      for (int rr = 0; rr < 4; ++rr) {
        int t = t0 + wr * 64 + i * 16 + (lane >> 4) * 4 + rr;
        int m = m0 + wc * 64 + j * 16 + (lane & 15);
        size_t idx = ((size_t)b * T_ + t) * M_ + m;
        float en = acc[i][j][rr] * (1.0f / 512.0f);
        float u  = noise[idx];
        float nl = -LN2 * __builtin_amdgcn_logf(u);    // -ln u  (>0)
        float g  = -LN2 * __builtin_amdgcn_logf(nl);   // -ln(-ln u)
        log_e[idx] = (en + g) * invT;
      }
    }
  }
}

// ---------------------------------------------------------------------------
// K2: log_S = reverse cumulative LSE of log_e along m (per row). 256 thr/row.
// ---------------------------------------------------------------------------
__launch_bounds__(256)
__global__ void k2_logS(const float* __restrict__ log_e, float* __restrict__ log_S)
{
  const size_t row = blockIdx.x;          // b*T + t
  const float* src = log_e + row * M_;
  float* dst = log_S + row * M_;
  const int tid = threadIdx.x, lane = tid & 63, wid = tid >> 6;
  const int c0 = tid * 8;
  float x[8];
  float4 xa = *(const float4*)(src + c0);
  float4 xb = *(const float4*)(src + c0 + 4);
  x[0] = xa.x; x[1] = xa.y; x[2] = xa.z; x[3] = xa.w;
  x[4] = xb.x; x[5] = xb.y; x[6] = xb.z; x[7] = xb.w;
#pragma unroll
  for (int i = 6; i >= 0; --i) x[i] = lae(x[i], x[i + 1]);  // local suffix incl
  float v = x[0];
#pragma unroll
  for (int d = 1; d < 64; d <<= 1) {
    float w = __shfl_down(v, d);
    if (lane < 64 - d) v = lae(v, w);
  }
  float e = __shfl_down(v, 1);
  if (lane == 63) e = NEGV;               // suffix over lanes strictly after
  __shared__ float part[4];
  if (lane == 0) part[wid] = v;
  __syncthreads();
  float we = NEGV;
  for (int w2 = wid + 1; w2 < 4; ++w2) we = lae(we, part[w2]);
  float off = lae(e, we);                 // LSE over cols >= c0+8
  float y[8];
#pragma unroll
  for (int i = 0; i < 8; ++i) y[i] = lae(x[i], off);
  *(float4*)(dst + c0)     = make_float4(y[0], y[1], y[2], y[3]);
  *(float4*)(dst + c0 + 4) = make_float4(y[4], y[5], y[6], y[7]);
}

// ---------------------------------------------------------------------------
// K3a: per-chunk partial sums of text over t (chunk = 64 rows)
// ---------------------------------------------------------------------------
__launch_bounds__(512)
__global__ void k3a_partial(const float* __restrict__ text, float* __restrict__ partial)
{
  const int b = blockIdx.x >> 3, ch = blockIdx.x & 7, c = threadIdx.x;
  const float* tb = text + (size_t)b * T_ * C_ + (size_t)ch * 64 * C_ + c;
  float s = 0.f;
#pragma unroll 8
  for (int tt = 0; tt < 64; ++tt) s += tb[(size_t)tt * C_];
  partial[((size_t)b * 8 + ch) * C_ + c] = s;
}

// ---------------------------------------------------------------------------
// K3b: suffix[b,t,c] = sum_{t'>=t} text[b,t',c]; layout [B][T+1][C], row T = 0
// ---------------------------------------------------------------------------
__launch_bounds__(512)
__global__ void k3b_suffix(const float* __restrict__ text, const float* __restrict__ partial,
                           float* __restrict__ suffix)
{
  const int b = blockIdx.x >> 3, ch = blockIdx.x & 7, c = threadIdx.x;
  float off = 0.f;
  for (int ch2 = ch + 1; ch2 < 8; ++ch2) off += partial[((size_t)b * 8 + ch2) * C_ + c];
  const float* tb = text + (size_t)b * T_ * C_ + (size_t)ch * 64 * C_ + c;
  float* sb = suffix + (size_t)b * (T_ + 1) * C_ + (size_t)ch * 64 * C_ + c;
  if (ch == 7) sb[(size_t)64 * C_] = 0.f;   // row T_
  float s = off;
  for (int tt = 63; tt >= 0; --tt) {
    s += tb[(size_t)tt * C_];
    sb[(size_t)tt * C_] = s;
  }
}

// ---------------------------------------------------------------------------
// K3t: textT[b,c,t] = bf16(text[b,t,c])  (LDS transpose tiles)
// ---------------------------------------------------------------------------
__launch_bounds__(256)
__global__ void k3t_textT(const float* __restrict__ text, u16* __restrict__ textT)
{
  __shared__ u16 tile[64][66];
  const int b  = blockIdx.z;
  const int t0 = blockIdx.x * 64;
  const int c0 = blockIdx.y * 64;
  const int tid = threadIdx.x;
  const int j = tid & 63, i4 = tid >> 6;
#pragma unroll
  for (int it = 0; it < 16; ++it) {
    int i = it * 4 + i4;
    tile[i][j] = f2bf(text[((size_t)b * T_ + t0 + i) * C_ + c0 + j]);
  }
  __syncthreads();
#pragma unroll
  for (int it = 0; it < 16; ++it) {
    int cc = it * 4 + i4;
    textT[((size_t)b * C_ + c0 + cc) * T_ + t0 + j] = tile[j][cc];
  }
}

// ---------------------------------------------------------------------------
// K4: alpha (blocks 0..15) / beta (blocks 16..31) DP. ONE WAVE per chain.
//     64 threads, 32 cols/lane, no LDS, no barriers. Log2-domain carried state
//     ww[e]; linear prefix with running reference Cv; DPP wave scan of totals.
//     Alpha: fixed-column frame; masked region decays to clamp floor and the
//     stored junk is masked in k6 (m >= t). Beta: reversed fixed-column frame.
// ---------------------------------------------------------------------------
__launch_bounds__(64, 1)
__global__ void k4_dp(const float* __restrict__ log_e, const float* __restrict__ log_S,
                      const float* __restrict__ ratio,
                      float* __restrict__ alpha_out, float* __restrict__ beta_out)
{
  const int blk = blockIdx.x;
  const int b   = blk & 15;
  const int lane = threadIdx.x & 63;
  const int c0 = lane * 32;
  const float invT = 1.0f / (0.1f + 0.9f * ratio[0]);
  const float KB  = 18.4413f * invT;
  const float KB2 = KB * L2E;
  const float* LE = log_e + (size_t)b * T_ * M_;
  const float* LS = log_S + (size_t)b * T_ * M_;

  float le[2][32], ls[2][32], ww[32], lg[32];
  float Cv, dC2;

  if (blk < 16) {
    // ======================= alpha =======================
    float* AO = alpha_out + (size_t)b * T_ * M_;

#define ALD(BUF, R) { const float* p_ = LE + (size_t)(R) * M_ + c0; \
    _Pragma("unroll") for (int g = 0; g < 8; ++g) { \
      float4 v_ = *(const float4*)(p_ + 4*g); \
      le[BUF][4*g+0]=v_.x; le[BUF][4*g+1]=v_.y; le[BUF][4*g+2]=v_.z; le[BUF][4*g+3]=v_.w; } }
#define ALS(BUF, R) { const float* p_ = LS + (size_t)(R) * M_ + c0; \
    _Pragma("unroll") for (int g = 0; g < 8; ++g) { \
      float4 v_ = *(const float4*)(p_ + 4*g); \
      ls[BUF][4*g+0]=v_.x; ls[BUF][4*g+1]=v_.y; ls[BUF][4*g+2]=v_.z; ls[BUF][4*g+3]=v_.w; } }

    ALD(0, 0) ALS(0, 0) ALD(1, 1) ALS(1, 1)
    Cv  = 3.6258f * invT + 1.0f;
    dC2 = -Cv * L2E;
#pragma unroll
    for (int e = 0; e < 32; ++e) ww[e] = NEGV;   // alpha_0[j>=1] = -inf (log2-capped)

#define ASTEP(BUF, RR) { \
    const int r_ = (RR); \
    /* ev[j] = exp2(alpha_r[j]*L2E - ls_r[j]*L2E - Cv*L2E); alpha_r[j] <- ww[e-1] (shift) */ \
    float w31s = __shfl_up(ww[31], 1); \
    float wm1 = (lane == 0) ? ((r_ == 0) ? 0.f : NEGV) : w31s; \
    float ev[32]; \
    { float a0 = __builtin_fmaf(ls[BUF][0], -L2E, wm1 + dC2); \
      ev[0] = __builtin_amdgcn_exp2f(a0); } \
    _Pragma("unroll") for (int e = 1; e < 32; ++e) { \
      float a_ = __builtin_fmaf(ls[BUF][e], -L2E, ww[e-1] + dC2); \
      ev[e] = __builtin_amdgcn_exp2f(a_); } \
    { const int rp = (r_ + 2 < T_) ? r_ + 2 : T_ - 1; ALS(BUF, rp) } \
    /* in-lane inclusive prefix, 4 chunks of 8 (in place) */ \
    _Pragma("unroll") for (int c = 0; c < 4; ++c) \
      _Pragma("unroll") for (int k = 1; k < 8; ++k) ev[8*c+k] += ev[8*c+k-1]; \
    float ct1 = ev[7], ct2 = ct1 + ev[15], ct3 = ct2 + ev[23]; \
    float Te = ct3 + ev[31]; \
    _Pragma("unroll") for (int k = 0; k < 7; ++k) { ev[8+k] += ct1; ev[16+k] += ct2; ev[24+k] += ct3; } \
    ev[15] = ct2; ev[23] = ct3; ev[31] = Te; \
    float v_ = wscan_add(Te); \
    float excl = v_ - Te; \
    float S = __shfl(v_, 63); \
    _Pragma("unroll") for (int e = 0; e < 32; ++e) { \
      float pf = fmaxf(excl + ev[e], 1e-30f); \
      lg[e] = __builtin_amdgcn_logf(pf); } \
    { float* op = AO + (size_t)r_ * M_ + c0; \
      _Pragma("unroll") for (int g = 0; g < 8; ++g) { \
        float4 o_; \
        o_.x = __builtin_fmaf(lg[4*g+0], LN2, le[BUF][4*g+0] + Cv); \
        o_.y = __builtin_fmaf(lg[4*g+1], LN2, le[BUF][4*g+1] + Cv); \
        o_.z = __builtin_fmaf(lg[4*g+2], LN2, le[BUF][4*g+2] + Cv); \
        o_.w = __builtin_fmaf(lg[4*g+3], LN2, le[BUF][4*g+3] + Cv); \
        *(float4*)(op + 4*g) = o_; } } \
    float Sc = fmaxf(S, 1e-30f); \
    float lgS = __builtin_amdgcn_logf(Sc); \
    dC2 = -lgS - KB2; \
    Cv  = __builtin_fmaf(lgS, LN2, Cv + KB); \
    _Pragma("unroll") for (int e = 0; e < 32; ++e) \
      ww[e] = __builtin_fmaf(le[BUF][e], L2E, lg[e]); \
    { const int rp = (r_ + 2 < T_) ? r_ + 2 : T_ - 1; ALD(BUF, rp) } \
  }

    for (int r = 0; r < T_; r += 2) {
      ASTEP(0, r)
      ASTEP(1, r + 1)
    }
  } else {
    // ======================= beta (reversed frame) =======================
    float* BO = beta_out + (size_t)b * T_ * M_;
    const int jb = M_ - 32 - c0;   // element e <-> column j = M-1-c0-e = jb + 31 - e

#define BLD(BUF, R) { const float* p_ = LE + (size_t)(R) * M_ + jb; \
    _Pragma("unroll") for (int g = 0; g < 8; ++g) { \
      float4 v_ = *(const float4*)(p_ + 4*g); \
      le[BUF][31-4*g]=v_.x; le[BUF][30-4*g]=v_.y; le[BUF][29-4*g]=v_.z; le[BUF][28-4*g]=v_.w; } }
#define BLS(BUF, R) { const float* p_ = LS + (size_t)(R) * M_ + jb; \
    _Pragma("unroll") for (int g = 0; g < 8; ++g) { \
      float4 v_ = *(const float4*)(p_ + 4*g); \
      ls[BUF][31-4*g]=v_.x; ls[BUF][30-4*g]=v_.y; ls[BUF][29-4*g]=v_.z; ls[BUF][28-4*g]=v_.w; } }

    // init row T-1: zeros, 1.0 at j = M-1 (faithful odd init)
    { float* op = BO + (size_t)(T_ - 1) * M_ + jb;
      float4 z4 = make_float4(0.f, 0.f, 0.f, 0.f);
#pragma unroll
      for (int g = 0; g < 7; ++g) *(float4*)(op + 4*g) = z4;
      *(float4*)(op + 28) = make_float4(0.f, 0.f, 0.f, (lane == 0) ? 1.f : 0.f);
    }

    BLD(0, T_ - 2) BLS(0, T_ - 2) BLD(1, T_ - 3) BLS(1, T_ - 3)
    Cv  = 14.8155f * invT + 1.5f;
    dC2 = -Cv * L2E;
#pragma unroll
    for (int e = 0; e < 32; ++e) ww[e] = 0.f;
    if (lane == 0) ww[0] = L2E;   // beta_{T-1}[M-1] = 1.0 (log-domain, faithful)

#define BSTEP(BUF, TT) { \
    const int t_ = (TT); \
    float ev[32]; \
    _Pragma("unroll") for (int e = 0; e < 32; ++e) { \
      float a_ = __builtin_fmaf(le[BUF][e], L2E, ww[e] + dC2); \
      ev[e] = __builtin_amdgcn_exp2f(a_); } \
    { const int tp = (t_ - 2 >= 0) ? t_ - 2 : 0; BLD(BUF, tp) } \
    _Pragma("unroll") for (int c = 0; c < 4; ++c) \
      _Pragma("unroll") for (int k = 1; k < 8; ++k) ev[8*c+k] += ev[8*c+k-1]; \
    float ct1 = ev[7], ct2 = ct1 + ev[15], ct3 = ct2 + ev[23]; \
    float Te = ct3 + ev[31]; \
    _Pragma("unroll") for (int k = 0; k < 7; ++k) { ev[8+k] += ct1; ev[16+k] += ct2; ev[24+k] += ct3; } \
    ev[15] = ct2; ev[23] = ct3; ev[31] = Te; \
    float v_ = wscan_add(Te); \
    float excl = v_ - Te; \
    float S = __shfl(v_, 63); \
    _Pragma("unroll") for (int e = 0; e < 32; ++e) { \
      float pf = fmaxf(excl + ev[e], 1e-30f); \
      lg[e] = __builtin_amdgcn_logf(pf); } \
    { float* op = BO + (size_t)t_ * M_ + jb; \
      _Pragma("unroll") for (int g = 0; g < 8; ++g) { \
        float4 o_; \
        o_.x = __builtin_fmaf(lg[31-4*g], LN2, Cv) - ls[BUF][31-4*g]; \
        o_.y = __builtin_fmaf(lg[30-4*g], LN2, Cv) - ls[BUF][30-4*g]; \
        o_.z = __builtin_fmaf(lg[29-4*g], LN2, Cv) - ls[BUF][29-4*g]; \
        o_.w = __builtin_fmaf(lg[28-4*g], LN2, Cv) - ls[BUF][28-4*g]; \
        *(float4*)(op + 4*g) = o_; } } \
    float Sc = fmaxf(S, 1e-30f); \
    float lgS = __builtin_amdgcn_logf(Sc); \
    dC2 = -lgS - KB2; \
    Cv  = __builtin_fmaf(lgS, LN2, Cv + KB); \
    _Pragma("unroll") for (int e = 0; e < 32; ++e) \
      ww[e] = __builtin_fmaf(ls[BUF][e], -L2E, lg[e]); \
    { const int tp = (t_ - 2 >= 0) ? t_ - 2 : 0; BLS(BUF, tp) } \
  }

    for (int t = T_ - 2; t >= 0; t -= 2) {
      BSTEP(0, t)
      if (t > 0) BSTEP(1, t - 1)
    }
  }
}

// ---------------------------------------------------------------------------
// K6: gamma = (m>=t) ? alpha+beta : NEGV; LSE over t; gamma_log in-place over
//     alpha; gammaT[b,m,t] = bf16(gamma) masked (NEG -> 0), via LDS transpose.
// ---------------------------------------------------------------------------
__launch_bounds__(256)
__global__ void k6_combine(float* __restrict__ alpha_gl, const float* __restrict__ beta,
                           u16* __restrict__ gammaT)
{
  __shared__ float smx[4][64], ssm[4][64];
  __shared__ u16 gtile[64][66];
  const int b  = blockIdx.x >> 5;
  const int m0 = (blockIdx.x & 31) * 64;
  const int tid = threadIdx.x;
  const int mi = tid & 63, ti = tid >> 6;
  const int m = m0 + mi;
  const size_t base = (size_t)b * T_ * M_ + m;

  float mx = -3.0e38f, s = 0.f;
  for (int t = ti; t < T_; t += 4) {
    float a = alpha_gl[base + (size_t)t * M_];
    float bt = beta[base + (size_t)t * M_];
    float g = (t <= m) ? (a + bt) : NEGV;
    if (g > mx) { s = s * __builtin_amdgcn_exp2f((mx - g) * L2E) + 1.f; mx = g; }
    else        { s += __builtin_amdgcn_exp2f((g - mx) * L2E); }
  }
  smx[ti][mi] = mx; ssm[ti][mi] = s;
  __syncthreads();
  float Mv = smx[0][mi], Sv = ssm[0][mi];
#pragma unroll
  for (int k = 1; k < 4; ++k) {
    float Mk = smx[k][mi], Sk = ssm[k][mi];
    if (Mk > Mv) { Sv = Sv * __builtin_amdgcn_exp2f((Mv - Mk) * L2E) + Sk; Mv = Mk; }
    else         { Sv += Sk * __builtin_amdgcn_exp2f((Mk - Mv) * L2E); }
  }
  const float lse = Mv + LN2 * __builtin_amdgcn_logf(Sv);

  for (int tc = 0; tc < T_; tc += 64) {
    for (int tt = ti; tt < 64; tt += 4) {
      int t = tc + tt;
      size_t idx = base + (size_t)t * M_;
      float a = alpha_gl[idx];
      float bt = beta[idx];
      float g = (t <= m) ? (a + bt) : NEGV;
      alpha_gl[idx] = g - lse;                       // gamma_log in-place
      gtile[mi][tt] = (g <= -1e29f) ? (u16)0 : f2bf(g);
    }
    __syncthreads();
#pragma unroll
    for (int it = 0; it < 16; ++it) {
      int rr = it * 4 + ti;
      gammaT[((size_t)b * M_ + m0 + rr) * T_ + tc + mi] = gtile[rr][mi];
    }
    __syncthreads();
  }
}

// ---------------------------------------------------------------------------
// K7: expanded[b,m,c] = sum_t gammaT[m,t]*textT[c,t]  + (-1e30)*suffix[m+1,c]
// ---------------------------------------------------------------------------
__launch_bounds__(256)
__global__ void k7_expanded(const u16* __restrict__ gammaT, const u16* __restrict__ textT,
                            const float* __restrict__ suffix, float* __restrict__ expanded)
{
  __shared__ __align__(16) short As[128][40];
  __shared__ __align__(16) short Bs[128][40];
  const int b   = blockIdx.z;
  const int m0  = blockIdx.x * 128;
  const int c0  = blockIdx.y * 128;
  const int tid = threadIdx.x;
  const int lane = tid & 63, wid = tid >> 6;
  const int wr = wid >> 1, wc = wid & 1;
  const u16* Ab = gammaT + (size_t)b * M_ * T_;
  const u16* Bb = textT  + (size_t)b * C_ * T_;
  f32x4 acc[4][4];
#pragma unroll
  for (int i = 0; i < 4; ++i)
#pragma unroll
    for (int j = 0; j < 4; ++j) acc[i][j] = (f32x4){0.f, 0.f, 0.f, 0.f};

  const int ko  = (tid & 3) * 8;
  const int rb2 = tid >> 2;
  for (int kk = 0; kk < T_; kk += 32) {
    __syncthreads();
#pragma unroll
    for (int it = 0; it < 2; ++it) {
      int r = rb2 + it * 64;
      *(uint4*)&As[r][ko] = *(const uint4*)(Ab + (size_t)(m0 + r) * T_ + kk + ko);
      *(uint4*)&Bs[r][ko] = *(const uint4*)(Bb + (size_t)(c0 + r) * T_ + kk + ko);
    }
    __syncthreads();
    const int k0 = (lane >> 4) * 8;
    bf16x8 af[4], bfr[4];
#pragma unroll
    for (int i = 0; i < 4; ++i) {
      af[i]  = *(const bf16x8*)&As[wr * 64 + i * 16 + (lane & 15)][k0];
      bfr[i] = *(const bf16x8*)&Bs[wc * 64 + i * 16 + (lane & 15)][k0];
    }
#pragma unroll
    for (int i = 0; i < 4; ++i)
#pragma unroll
      for (int j = 0; j < 4; ++j)
        acc[i][j] = __builtin_amdgcn_mfma_f32_16x16x32_bf16(af[i], bfr[j], acc[i][j], 0, 0, 0);
  }
#pragma unroll
  for (int i = 0; i < 4; ++i) {
#pragma unroll
    for (int j = 0; j < 4; ++j) {
#pragma unroll
      for (int rr = 0; rr < 4; ++rr) {
        int m = m0 + wr * 64 + i * 16 + (lane >> 4) * 4 + rr;
        int c = c0 + wc * 64 + j * 16 + (lane & 15);
        int sidx = (m + 1 < T_) ? (m + 1) : T_;
        float sfx = suffix[((size_t)b * (T_ + 1) + sidx) * C_ + c];
        expanded[((size_t)b * M_ + m) * C_ + c] = acc[i][j][rr] + NEGV * sfx;
      }
    }
  }
}

// ---------------------------------------------------------------------------
extern "C" void kernel_launch(void* const* d_in, const int* in_sizes, int n_in,
                              void* d_out, int out_size, void* d_ws, size_t ws_size,
                              hipStream_t stream) {
  const float* text  = (const float*)d_in[0];
  const float* mel   = (const float*)d_in[1];
  const float* noise = (const float*)d_in[2];
  const float* ratio = (const float*)d_in[3];

  const size_t BTM = (size_t)B_ * T_ * M_;   // 16777216
  float* out       = (float*)d_out;
  float* gamma_log = out;                    // also alpha scratch
  float* expanded  = out + BTM;              // also beta scratch

  char* w = (char*)d_ws;
  float* log_e  = (float*)(w + 0);
  float* log_S  = (float*)(w + 67108864);
  float* suffix = (float*)(w + 134217728);   // [B][T+1][C]  16809984 B
  u16*   textT  = (u16*)  (w + 151027712);   // [B][C][T]     8388608 B
  u16*   gammaT = (u16*)  (w + 159416320);   // [B][M][T]    33554432 B
  float* partial = (float*)(w + 0);          // k3 scratch, reuses log_e region (before k1)

  k3a_partial<<<B_ * 8,          512, 0, stream>>>(text, partial);
  k3b_suffix <<<B_ * 8,          512, 0, stream>>>(text, partial, suffix);
  k3t_textT  <<<dim3(8, 8, 16),  256, 0, stream>>>(text, textT);
  k1_energy  <<<dim3(4, 16, 16), 256, 0, stream>>>(text, mel, noise, ratio, log_e);
  k2_logS    <<<B_ * T_,         256, 0, stream>>>(log_e, log_S);
  k4_dp      <<<32,               64, 0, stream>>>(log_e, log_S, ratio, gamma_log, expanded);
  k6_combine <<<B_ * 32,         256, 0, stream>>>(gamma_log, expanded, gammaT);
  k7_expanded<<<dim3(16, 4, 16), 256, 0, stream>>>(gammaT, textT, suffix, expanded);
}